// Round 6
// baseline (230.301 us; speedup 1.0000x reference)
//
#include <hip/hip_runtime.h>

#define BS 4096
#define LL 512
#define CC 4
#define SS (LL / CC)          // 128 steps per chunk
#define START_TAG 1
#define END_TAG 2
#define BIASF 4.5f            // per-applied-step 2^-BIASF scaling (restored exactly)
#define L2E 1.44269504f

typedef float f32x4 __attribute__((ext_vector_type(4)));
typedef short s16x4 __attribute__((ext_vector_type(4)));
union BF4 { unsigned u[2]; s16x4 s; };

__device__ __forceinline__ unsigned cvt_pk_bf16(float lo, float hi) {
    unsigned r;
    asm("v_cvt_pk_bf16_f32 %0, %1, %2" : "=v"(r) : "v"(lo), "v"(hi));
    return r;
}

// Block = one batch. Wave c of 4 computes chunk c's 16x16 product matrix:
//   M_c = prod_{t in chunk, mask=1} diag(e^em_t * 2^-BIASF) * E^T   (E = exp(tr))
// via one v_mfma_f32_16x16x16_bf16 per step with STATIC A = E^T; D-rows scaled
// by this lane's own em float4 (no cross-lane traffic). Chunks combined in LDS.
__global__ __launch_bounds__(256, 4) void crf_mat(
    const float* __restrict__ em, const int* __restrict__ tg,
    const float* __restrict__ mk, const float* __restrict__ tr,
    float* __restrict__ out)
{
    const int b    = blockIdx.x;
    const int wv   = threadIdx.x >> 6;   // chunk id
    const int lane = threadIdx.x & 63;
    const int j    = lane & 15;          // matrix col of B/D, row of A
    const int q    = lane >> 4;          // row-block: this lane owns rows 4q..4q+3

    __shared__ float s_tr[256];
    __shared__ float sP[CC][16][16];
    __shared__ float sO[CC], sSc[CC], sCnt[CC];

    if (threadIdx.x < 64)
        *(f32x4*)(s_tr + threadIdx.x * 4) = *(const f32x4*)(tr + threadIdx.x * 4);
    __syncthreads();

    // tags dtype detect (validated): 16 u64 words all <16 => int64 layout
    int is64 = 1;
    {
        const unsigned long long* t64 = (const unsigned long long*)tg;
#pragma unroll
        for (int i = 0; i < 16; ++i) is64 &= (t64[i] < 16ull) ? 1 : 0;
    }
    const int esz = is64 ? 2 : 1;

    // Static A = E^T: lane (j,q) holds A[j][4q+i] = exp(tr[4q+i][j])
    BF4 Ab;
    {
        float Ef[4];
#pragma unroll
        for (int i = 0; i < 4; ++i)
            Ef[i] = expf(s_tr[(q * 4 + i) * 16 + j]);   // exp(-1000) -> exact 0
        Ab.u[0] = cvt_pk_bf16(Ef[0], Ef[1]);
        Ab.u[1] = cvt_pk_bf16(Ef[2], Ef[3]);
    }

    // State: bf16 B fragment + f32 mirror, init identity
    unsigned p01 = ((q*4+0 == j) ? 0x3F80u : 0u) | (((q*4+1 == j) ? 0x3F80u : 0u) << 16);
    unsigned p23 = ((q*4+2 == j) ? 0x3F80u : 0u) | (((q*4+3 == j) ? 0x3F80u : 0u) << 16);
    f32x4 d;
#pragma unroll
    for (int i = 0; i < 4; ++i) d[i] = (q*4+i == j) ? 1.f : 0.f;

    float e2f = 0.f, cnt = 0.f, sc = 0.f;
    const long bb = (long)b * LL;
    const int  t0 = wv * SS;
    int tprev = (wv == 0) ? START_TAG : (int)tg[(bb + t0 - 1) * esz];

    const float* emp = em + ((bb + t0) << 4) + (q << 2);  // em[b][t][4q..4q+3]
    const float* mkp = mk + bb + t0;
    const int*   tgp = tg + (bb + t0) * esz;

#pragma unroll 4
    for (int g = 0; g < SS; ++g) {
        const f32x4 ev  = *(const f32x4*)(emp + (g << 4));
        const float um  = mkp[g];                 // wave-uniform
        const int   tcur = tgp[g * esz];
        const int   t   = t0 + g;
        const float scm = (t == 0) ? 1.f : um;
        const int   tpv = (t == 0) ? START_TAG : tprev;
        if (j == 0 && (tcur >> 2) == q) {         // fused path-score gather
            const float es = (tcur & 2) ? ((tcur & 1) ? ev.w : ev.z)
                                        : ((tcur & 1) ? ev.y : ev.x);
            sc = fmaf(es + s_tr[tpv * 16 + tcur], scm, sc);
        }
        tprev = tcur;
        cnt += um;                                // uniform across lanes

        if (um > 0.f) {                           // wave-uniform branch
            const float e0 = exp2f(fmaf(ev.x, L2E, -BIASF));
            const float e1 = exp2f(fmaf(ev.y, L2E, -BIASF));
            const float e2 = exp2f(fmaf(ev.z, L2E, -BIASF));
            const float e3 = exp2f(fmaf(ev.w, L2E, -BIASF));
            BF4 Bp; Bp.u[0] = p01; Bp.u[1] = p23;
            f32x4 z = {0.f, 0.f, 0.f, 0.f};
            f32x4 nd = __builtin_amdgcn_mfma_f32_16x16x16bf16_1k(Ab.s, Bp.s, z, 0, 0, 0);
            nd[0] *= e0; nd[1] *= e1; nd[2] *= e2; nd[3] *= e3;
            p01 = cvt_pk_bf16(nd[0], nd[1]);      // D layout == B layout
            p23 = cvt_pk_bf16(nd[2], nd[3]);
            d = nd;
        }

        // exact power-of-2 renorm every 32 steps (validated cadence/BIAS)
        if ((g & 31) == 31 && g != SS - 1) {
            float mm = fmaxf(fmaxf(d[0], d[1]), fmaxf(d[2], d[3]));
#pragma unroll
            for (int o = 1; o <= 32; o <<= 1) mm = fmaxf(mm, __shfl_xor(mm, o));
            if (mm > 0.f) {
                const int ex = (int)((__float_as_uint(mm) >> 23) & 0xFFu) - 127;
                const float s = __uint_as_float((unsigned)(127 - ex) << 23);
                e2f += (float)ex;
                d[0] *= s; d[1] *= s; d[2] *= s; d[3] *= s;
                p01 = cvt_pk_bf16(d[0], d[1]);
                p23 = cvt_pk_bf16(d[2], d[3]);
            }
        }
    }

    // chunk matrix -> LDS: sP[c][row=4q+i][col=j]
#pragma unroll
    for (int i = 0; i < 4; ++i) sP[wv][q * 4 + i][j] = d[i];

    sc += __shfl_xor(sc, 16);                     // score partials live on j==0 lanes
    sc += __shfl_xor(sc, 32);
    if (lane == 0) {
        sSc[wv]  = sc;
        sCnt[wv] = cnt;
        sO[wv]   = e2f + BIASF * cnt;             // exact log2 offset of this chunk
    }
    __syncthreads();

    // ---- combine on lanes 0..15: alpha = M3*M2*M1*M0 * ones ----
    if (threadIdx.x < 16) {
        const int jj = threadIdx.x;
        float w = 1.f, l2 = 0.f;
        for (int c = 0; c < CC; ++c) {
            float nw = 0.f;
#pragma unroll
            for (int i = 0; i < 16; ++i)
                nw = fmaf(sP[c][jj][i], __shfl(w, i, 16), nw);
            float m = nw;
#pragma unroll
            for (int o = 1; o <= 8; o <<= 1) m = fmaxf(m, __shfl_xor(m, o, 16));
            m = fmaxf(m, 1e-30f);
            l2 += log2f(m);
            w = nw / m;
        }
        float ot = 0.f, scT = 0.f, cntT = 0.f;
#pragma unroll
        for (int c = 0; c < CC; ++c) { ot += sO[c]; scT += sSc[c]; cntT += sCnt[c]; }

        float y = log2f(w) + l2 + ot + s_tr[jj * 16 + END_TAG] * L2E;
        float m2 = y;
#pragma unroll
        for (int o = 1; o <= 8; o <<= 1) m2 = fmaxf(m2, __shfl_xor(m2, o, 16));
        m2 = fmaxf(m2, -1e30f);
        float e = exp2f(y - m2);
#pragma unroll
        for (int o = 1; o <= 8; o <<= 1) e += __shfl_xor(e, o, 16);
        const float dp = (m2 + log2f(e)) * 0.69314718055994531f;

        if (jj == 0) {
            const int li = (int)cntT - 1;
            const int lt = tg[(bb + li) * esz];
            atomicAdd(out, dp - (scT + s_tr[lt * 16 + END_TAG]));
        }
    }
}

extern "C" void kernel_launch(void* const* d_in, const int* in_sizes, int n_in,
                              void* d_out, int out_size, void* d_ws, size_t ws_size,
                              hipStream_t stream) {
    const float* em = (const float*)d_in[0];
    const int*   tg = (const int*)d_in[1];
    const float* mk = (const float*)d_in[2];
    const float* tr = (const float*)d_in[3];
    float* out = (float*)d_out;

    hipMemsetAsync(out, 0, sizeof(float), stream);
    crf_mat<<<BS, 256, 0, stream>>>(em, tg, mk, tr, out);
}

// Round 7
// 112.522 us; speedup vs baseline: 2.0467x; 2.0467x over previous
//
#include <hip/hip_runtime.h>

#define BS 4096
#define LL 512
#define CC 4
#define SS (LL / CC)          // 128 steps per wave-chunk
#define START_TAG 1
#define END_TAG 2
#define BIASF 4.5f            // per-applied-step 2^-BIASF scaling (restored exactly)
#define L2E 1.44269504f

typedef float f32x4 __attribute__((ext_vector_type(4)));
typedef short s16x4 __attribute__((ext_vector_type(4)));
union BF4 { unsigned u[2]; s16x4 s; };

__device__ __forceinline__ unsigned cvt_pk_bf16(float lo, float hi) {
    unsigned r;
    asm("v_cvt_pk_bf16_f32 %0, %1, %2" : "=v"(r) : "v"(lo), "v"(hi));
    return r;
}

// Block = one batch.
// Phase 1 (all 256 thr): scales sE[t][r] = e^{em[t][r]} * 2^-BIASF -> LDS (f32),
//                        mask -> LDS, full path-score + mask-count block-reduced.
// Phase 2 (wave c of 4): chunk product M_c = prod_t diag(sE_t) * E^T  via one
//   static-A MFMA per step; D-rows scaled by ds_read_b128 of sE (no trans ops).
// Combine (16 lanes): alpha = M3*M2*M1*M0 * ones, logsumexp, atomicAdd.
__global__ __launch_bounds__(256, 4) void crf_pre(
    const float* __restrict__ em, const int* __restrict__ tg,
    const float* __restrict__ mk, const float* __restrict__ tr,
    float* __restrict__ out)
{
    __shared__ float sE[LL * 16];        // 32 KB precomputed scales
    __shared__ float sMk[LL];            // 2 KB
    __shared__ float s_tr[256];          // 1 KB
    __shared__ float sP[CC][16][16];     // 4 KB chunk matrices
    __shared__ float sO[CC];             // renorm exponent sums
    __shared__ float sRed[8];            // score/cnt wave partials

    const int tid  = threadIdx.x;
    const int wv   = tid >> 6;
    const int lane = tid & 63;
    const int j    = lane & 15;
    const int q    = lane >> 4;
    const int b    = blockIdx.x;
    const long bb  = (long)b * LL;

    if (tid < 64) *(f32x4*)(s_tr + tid * 4) = *(const f32x4*)(tr + tid * 4);

    // tags dtype detect (validated): 16 u64 words all <16 => int64 layout
    int is64 = 1;
    {
        const unsigned long long* t64 = (const unsigned long long*)tg;
#pragma unroll
        for (int i = 0; i < 16; ++i) is64 &= (t64[i] < 16ull) ? 1 : 0;
    }
    const int esz = is64 ? 2 : 1;

    // ---- phase 1a: em -> exp scales (coalesced f32x4), mask -> LDS ----
    const float* emb = em + (bb << 4);
#pragma unroll
    for (int k = 0; k < 8; ++k) {
        const int idx = (tid << 2) + (k << 10);
        const f32x4 v = *(const f32x4*)(emb + idx);
        f32x4 e;
        e.x = exp2f(fmaf(v.x, L2E, -BIASF));
        e.y = exp2f(fmaf(v.y, L2E, -BIASF));
        e.z = exp2f(fmaf(v.z, L2E, -BIASF));
        e.w = exp2f(fmaf(v.w, L2E, -BIASF));
        *(f32x4*)(sE + idx) = e;
    }
    if (tid < 128) *(f32x4*)(sMk + tid * 4) = *(const f32x4*)(mk + bb + tid * 4);
    __syncthreads();

    // ---- phase 1b: path score + mask count (2 steps/thread, block reduce) ----
    float part = 0.f, cpart = 0.f;
#pragma unroll
    for (int k = 0; k < 2; ++k) {
        const int t    = tid + (k << 8);
        const int tcur = tg[(bb + t) * esz];
        const int tpv  = (t == 0) ? START_TAG : (int)tg[(bb + t - 1) * esz];
        const float m  = sMk[t];
        const float scm = (t == 0) ? 1.f : m;
        part = fmaf(em[((bb + t) << 4) + tcur] + s_tr[tpv * 16 + tcur], scm, part);
        cpart += m;
    }
#pragma unroll
    for (int o = 1; o <= 32; o <<= 1) {
        part  += __shfl_xor(part, o);
        cpart += __shfl_xor(cpart, o);
    }
    if (lane == 0) { sRed[wv] = part; sRed[4 + wv] = cpart; }

    // ---- phase 2: chunk product, static A = E^T ----
    BF4 Ab;
    {
        float Ef[4];
#pragma unroll
        for (int i = 0; i < 4; ++i)
            Ef[i] = expf(s_tr[(q * 4 + i) * 16 + j]);   // exp(-1000) -> exact 0
        Ab.u[0] = cvt_pk_bf16(Ef[0], Ef[1]);
        Ab.u[1] = cvt_pk_bf16(Ef[2], Ef[3]);
    }

    unsigned p01 = ((q*4+0 == j) ? 0x3F80u : 0u) | (((q*4+1 == j) ? 0x3F80u : 0u) << 16);
    unsigned p23 = ((q*4+2 == j) ? 0x3F80u : 0u) | (((q*4+3 == j) ? 0x3F80u : 0u) << 16);
    f32x4 d;
#pragma unroll
    for (int i = 0; i < 4; ++i) d[i] = (q*4+i == j) ? 1.f : 0.f;

    float e2f = 0.f;
    const float* pE = sE + (wv * SS) * 16 + (q << 2);
    const float* pM = sMk + wv * SS;

    for (int g = 0; g < SS; g += 4) {
        const f32x4 m4 = *(const f32x4*)(pM + g);
#pragma unroll
        for (int s = 0; s < 4; ++s) {
            const float um = (s == 0) ? m4.x : (s == 1) ? m4.y : (s == 2) ? m4.z : m4.w;
            if (um > 0.f) {                                  // wave-uniform in practice
                const f32x4 s4 = *(const f32x4*)(pE + ((g + s) << 4));
                BF4 Bp; Bp.u[0] = p01; Bp.u[1] = p23;
                f32x4 z = {0.f, 0.f, 0.f, 0.f};
                f32x4 nd = __builtin_amdgcn_mfma_f32_16x16x16bf16_1k(Ab.s, Bp.s, z, 0, 0, 0);
                nd[0] *= s4.x; nd[1] *= s4.y; nd[2] *= s4.z; nd[3] *= s4.w;
                p01 = cvt_pk_bf16(nd[0], nd[1]);             // D layout == B layout
                p23 = cvt_pk_bf16(nd[2], nd[3]);
                d = nd;
            }
        }
        // exact power-of-2 renorm every 32 steps (validated cadence)
        if (((g + 4) & 31) == 0 && (g + 4) < SS) {
            float mm = fmaxf(fmaxf(d[0], d[1]), fmaxf(d[2], d[3]));
#pragma unroll
            for (int o = 1; o <= 32; o <<= 1) mm = fmaxf(mm, __shfl_xor(mm, o));
            if (mm > 0.f) {
                const int ex = (int)((__float_as_uint(mm) >> 23) & 0xFFu) - 127;
                const float sre = __uint_as_float((unsigned)(127 - ex) << 23);
                e2f += (float)ex;
                d[0] *= sre; d[1] *= sre; d[2] *= sre; d[3] *= sre;
                p01 = cvt_pk_bf16(d[0], d[1]);
                p23 = cvt_pk_bf16(d[2], d[3]);
            }
        }
    }

#pragma unroll
    for (int i = 0; i < 4; ++i) sP[wv][q * 4 + i][j] = d[i];
    if (lane == 0) sO[wv] = e2f;
    __syncthreads();

    // ---- combine on lanes 0..15: alpha = M3*M2*M1*M0 * ones ----
    if (tid < 16) {
        const int jj = tid;
        float w = 1.f, l2 = 0.f;
        for (int c = 0; c < CC; ++c) {
            float nw = 0.f;
#pragma unroll
            for (int i = 0; i < 16; ++i)
                nw = fmaf(sP[c][jj][i], __shfl(w, i, 16), nw);
            float m = nw;
#pragma unroll
            for (int o = 1; o <= 8; o <<= 1) m = fmaxf(m, __shfl_xor(m, o, 16));
            m = fmaxf(m, 1e-30f);
            l2 += log2f(m);
            w = nw / m;
        }
        const float scT  = sRed[0] + sRed[1] + sRed[2] + sRed[3];
        const float cntT = sRed[4] + sRed[5] + sRed[6] + sRed[7];
        const float ot   = sO[0] + sO[1] + sO[2] + sO[3] + BIASF * cntT;

        float y = log2f(w) + l2 + ot + s_tr[jj * 16 + END_TAG] * L2E;
        float m2 = y;
#pragma unroll
        for (int o = 1; o <= 8; o <<= 1) m2 = fmaxf(m2, __shfl_xor(m2, o, 16));
        m2 = fmaxf(m2, -1e30f);
        float e = exp2f(y - m2);
#pragma unroll
        for (int o = 1; o <= 8; o <<= 1) e += __shfl_xor(e, o, 16);
        const float dp = (m2 + log2f(e)) * 0.69314718055994531f;

        if (jj == 0) {
            const int li = (int)cntT - 1;
            const int lt = tg[(bb + li) * esz];
            atomicAdd(out, dp - (scT + s_tr[lt * 16 + END_TAG]));
        }
    }
}

extern "C" void kernel_launch(void* const* d_in, const int* in_sizes, int n_in,
                              void* d_out, int out_size, void* d_ws, size_t ws_size,
                              hipStream_t stream) {
    const float* em = (const float*)d_in[0];
    const int*   tg = (const int*)d_in[1];
    const float* mk = (const float*)d_in[2];
    const float* tr = (const float*)d_in[3];
    float* out = (float*)d_out;

    hipMemsetAsync(out, 0, sizeof(float), stream);
    crf_pre<<<BS, 256, 0, stream>>>(em, tg, mk, tr, out);
}

// Round 8
// 92.662 us; speedup vs baseline: 2.4854x; 1.2143x over previous
//
#include <hip/hip_runtime.h>

#define BS 4096
#define LL 512
#define CC 8
#define SS (LL / CC)          // 64 steps per wave-chunk
#define START_TAG 1
#define END_TAG 2
#define BIASF 4.5f            // per-applied-step 2^-BIASF scaling (restored exactly)
#define L2E 1.44269504f

typedef float f32x4 __attribute__((ext_vector_type(4)));
typedef float f32x2 __attribute__((ext_vector_type(2)));
typedef short s16x4 __attribute__((ext_vector_type(4)));
union BF4 { unsigned u[2]; s16x4 s; };

__device__ __forceinline__ unsigned cvt_pk_bf16(float lo, float hi) {
    unsigned r;
    asm("v_cvt_pk_bf16_f32 %0, %1, %2" : "=v"(r) : "v"(lo), "v"(hi));
    return r;
}

// Block = one batch, 8 waves = 8 time-chunks of 64 steps. Barrier-free until
// the final combine: each wave stages exp-scales + mask for ITS chunk into its
// own LDS region, then runs the chunk's 16x16 transfer-matrix product:
//   M_c = prod_t diag(e^{em_t} 2^-BIASF) * E^T     (E = exp(transition))
// one static-A bf16 MFMA per step, D-rows scaled by prefetched LDS scales.
// Combine on 16 lanes: alpha = M7...M0 * ones, logsumexp, one atomicAdd.
__global__ __launch_bounds__(512, 4) void crf_w8(
    const float* __restrict__ em, const int* __restrict__ tg,
    const float* __restrict__ mk, const float* __restrict__ tr,
    float* __restrict__ out)
{
    __shared__ float sE[LL * 16];        // 32 KB exp scales (f32)
    __shared__ float sMk[LL];            // 2 KB
    __shared__ float sP[CC][16][16];     // 8 KB chunk matrices
    __shared__ float sO[CC];             // renorm exponent sums
    __shared__ float sSc[CC], sCnt[CC];  // score / mask-count partials

    const int tid  = threadIdx.x;
    const int wv   = tid >> 6;           // wave = chunk id
    const int lane = tid & 63;
    const int j    = lane & 15;
    const int q    = lane >> 4;
    const long bb  = (long)blockIdx.x * LL;
    const int  t0  = wv * SS;

    // tags dtype detect (validated): 16 u64 words all <16 => int64 layout
    int is64 = 1;
    {
        const unsigned long long* t64 = (const unsigned long long*)tg;
#pragma unroll
        for (int i = 0; i < 16; ++i) is64 &= (t64[i] < 16ull) ? 1 : 0;
    }
    const int esz = is64 ? 2 : 1;

    // ---- stage own chunk: mask (64 f32) + exp scales (1024 f32) ----
    sMk[t0 + lane] = mk[bb + t0 + lane];
    {
        const int base = t0 * 16;                    // wave region: 1024 floats
        const float* emb = em + (bb << 4);
#pragma unroll
        for (int k = 0; k < 4; ++k) {
            const int idx = base + (lane << 2) + (k << 8);
            const f32x4 v = *(const f32x4*)(emb + idx);
            f32x4 e;
            e.x = exp2f(fmaf(v.x, L2E, -BIASF));
            e.y = exp2f(fmaf(v.y, L2E, -BIASF));
            e.z = exp2f(fmaf(v.z, L2E, -BIASF));
            e.w = exp2f(fmaf(v.w, L2E, -BIASF));
            *(f32x4*)(sE + idx) = e;
        }
    }

    // ---- path score + mask count: 1 step per lane (global reads, L1-hot) ----
    {
        const int t    = t0 + lane;
        const int tcur = tg[(bb + t) * esz];
        const int tpv  = (t == 0) ? START_TAG : (int)tg[(bb + t - 1) * esz];
        const float m  = mk[bb + t];
        const float scm = (t == 0) ? 1.f : m;
        float part  = fmaf(em[((bb + t) << 4) + tcur] + tr[tpv * 16 + tcur], scm, 0.f);
        float cpart = m;
#pragma unroll
        for (int o = 1; o <= 32; o <<= 1) {
            part  += __shfl_xor(part, o);
            cpart += __shfl_xor(cpart, o);
        }
        if (lane == 0) { sSc[wv] = part; sCnt[wv] = cpart; }
    }

    // ---- static A = E^T: lane (j,q) holds A[j][4q+i] = exp(tr[4q+i][j]) ----
    BF4 Ab;
    {
        float Ef[4];
#pragma unroll
        for (int i = 0; i < 4; ++i)
            Ef[i] = expf(tr[(q * 4 + i) * 16 + j]);   // exp(-1000) -> exact 0
        Ab.u[0] = cvt_pk_bf16(Ef[0], Ef[1]);
        Ab.u[1] = cvt_pk_bf16(Ef[2], Ef[3]);
    }

    // ---- chunk product: 64 steps, groups of 4 with prefetched scales ----
    unsigned p01 = ((q*4+0 == j) ? 0x3F80u : 0u) | (((q*4+1 == j) ? 0x3F80u : 0u) << 16);
    unsigned p23 = ((q*4+2 == j) ? 0x3F80u : 0u) | (((q*4+3 == j) ? 0x3F80u : 0u) << 16);
    f32x4 d;
#pragma unroll
    for (int i = 0; i < 4; ++i) d[i] = (q*4+i == j) ? 1.f : 0.f;
    float e2f = 0.f;

    const float* pE = sE + t0 * 16 + (q << 2);
    const float* pM = sMk + t0;

    for (int g = 0; g < SS; g += 4) {
        // prefetch group: mask (broadcast) + 4 scale vectors, ahead of the chain
        const f32x4 m4 = *(const f32x4*)(pM + g);
        f32x4 s4[4];
#pragma unroll
        for (int s = 0; s < 4; ++s) s4[s] = *(const f32x4*)(pE + ((g + s) << 4));

#pragma unroll
        for (int s = 0; s < 4; ++s) {
            const float um = m4[s];              // wave-uniform (one batch/block)
            if (um > 0.f) {
                BF4 Bp; Bp.u[0] = p01; Bp.u[1] = p23;
                f32x4 z = {0.f, 0.f, 0.f, 0.f};
                f32x4 nd = __builtin_amdgcn_mfma_f32_16x16x16bf16_1k(Ab.s, Bp.s, z, 0, 0, 0);
                nd[0] *= s4[s].x; nd[1] *= s4[s].y; nd[2] *= s4[s].z; nd[3] *= s4[s].w;
                p01 = cvt_pk_bf16(nd[0], nd[1]);  // D layout == B layout
                p23 = cvt_pk_bf16(nd[2], nd[3]);
                d = nd;
            }
        }

        // exact power-of-2 renorm every 32 steps (validated cadence)
        if (g + 4 == 32) {
            float mm = fmaxf(fmaxf(d[0], d[1]), fmaxf(d[2], d[3]));
#pragma unroll
            for (int o = 1; o <= 32; o <<= 1) mm = fmaxf(mm, __shfl_xor(mm, o));
            if (mm > 0.f) {
                const int ex = (int)((__float_as_uint(mm) >> 23) & 0xFFu) - 127;
                const float sre = __uint_as_float((unsigned)(127 - ex) << 23);
                e2f += (float)ex;
                d[0] *= sre; d[1] *= sre; d[2] *= sre; d[3] *= sre;
                p01 = cvt_pk_bf16(d[0], d[1]);
                p23 = cvt_pk_bf16(d[2], d[3]);
            }
        }
    }

#pragma unroll
    for (int i = 0; i < 4; ++i) sP[wv][q * 4 + i][j] = d[i];
    if (lane == 0) sO[wv] = e2f;
    __syncthreads();

    // ---- combine on lanes 0..15: alpha = M7*...*M0 * ones ----
    if (tid < 16) {
        const int jj = tid;
        float w = 1.f, l2 = 0.f;
#pragma unroll
        for (int c = 0; c < CC; ++c) {
            float nw = 0.f;
#pragma unroll
            for (int i = 0; i < 16; ++i)
                nw = fmaf(sP[c][jj][i], __shfl(w, i, 16), nw);
            float m = nw;
#pragma unroll
            for (int o = 1; o <= 8; o <<= 1) m = fmaxf(m, __shfl_xor(m, o, 16));
            m = fmaxf(m, 1e-30f);
            l2 += log2f(m);
            w = nw / m;
        }
        float scT = 0.f, cntT = 0.f, ot = 0.f;
#pragma unroll
        for (int c = 0; c < CC; ++c) { scT += sSc[c]; cntT += sCnt[c]; ot += sO[c]; }
        ot += BIASF * cntT;

        float y = log2f(w) + l2 + ot + tr[jj * 16 + END_TAG] * L2E;
        float m2 = y;
#pragma unroll
        for (int o = 1; o <= 8; o <<= 1) m2 = fmaxf(m2, __shfl_xor(m2, o, 16));
        m2 = fmaxf(m2, -1e30f);
        float e = exp2f(y - m2);
#pragma unroll
        for (int o = 1; o <= 8; o <<= 1) e += __shfl_xor(e, o, 16);
        const float dp = (m2 + log2f(e)) * 0.69314718055994531f;

        if (jj == 0) {
            const int li = (int)cntT - 1;
            const int lt = tg[(bb + li) * esz];
            atomicAdd(out, dp - (scT + tr[lt * 16 + END_TAG]));
        }
    }
}

extern "C" void kernel_launch(void* const* d_in, const int* in_sizes, int n_in,
                              void* d_out, int out_size, void* d_ws, size_t ws_size,
                              hipStream_t stream) {
    const float* em = (const float*)d_in[0];
    const int*   tg = (const int*)d_in[1];
    const float* mk = (const float*)d_in[2];
    const float* tr = (const float*)d_in[3];
    float* out = (float*)d_out;

    hipMemsetAsync(out, 0, sizeof(float), stream);
    crf_w8<<<BS, 512, 0, stream>>>(em, tg, mk, tr, out);
}